// Round 2
// baseline (11768.414 us; speedup 1.0000x reference)
//
#include <hip/hip_runtime.h>
#include <math.h>

#define SEQ 200
#define KTOT 431   // 44 ptr + 128 enc + 1 closest + 2 pred + 256 hx
#define NBLK 256

__device__ __forceinline__ float sigmoidf_(float x) { return 1.0f / (1.0f + __expf(-x)); }

// ---------------- W_out transpose: WoT[90][256] ----------------
__global__ void transpose_wout(const float* __restrict__ W_out, float* __restrict__ WoT) {
    int c = blockIdx.x;      // 0..89
    int k = threadIdx.x;     // 0..255
    WoT[c * 256 + k] = W_out[k * 90 + c];
}

// ---------------- Encoder + ptr transpose ----------------
__global__ __launch_bounds__(256) void enc_kernel(
    const float* __restrict__ coords,
    const float* __restrict__ W_e1, const float* __restrict__ b_e1,
    const float* __restrict__ W_e2, const float* __restrict__ b_e2,
    float* __restrict__ enc_ws, float* __restrict__ ptr_ws)
{
    __shared__ float C[64][89];
    __shared__ float H[64][2][65];
    __shared__ float W2[64][64];
    __shared__ float O[128][64];

    int t  = blockIdx.x >> 4;
    int bc = blockIdx.x & 15;
    int tid = threadIdx.x;

    for (int idx = tid; idx < 64 * 88; idx += 256) {
        int bl = idx / 88, j = idx - bl * 88;
        C[bl][j] = coords[((size_t)(bc * 64 + bl) * SEQ + t) * 88 + j];
    }
    for (int idx = tid; idx < 64 * 64; idx += 256)
        W2[idx >> 6][idx & 63] = W_e2[idx];
    __syncthreads();

    {
        int b  = tid >> 2;
        int cq = (tid & 3) * 16;
        float w0[16], w1[16], bb[16];
#pragma unroll
        for (int c = 0; c < 16; c++) { w0[c] = W_e1[cq + c]; w1[c] = W_e1[64 + cq + c]; bb[c] = b_e1[cq + c]; }
        for (int tm = 0; tm < 2; tm++) {
            float acc[16];
#pragma unroll
            for (int c = 0; c < 16; c++) acc[c] = 0.f;
            for (int p = 0; p < 11; p++) {
                float x = C[b][(tm * 11 + p) * 4];
                float y = C[b][(tm * 11 + p) * 4 + 1];
#pragma unroll
                for (int c = 0; c < 16; c++) {
                    float h = fmaf(x, w0[c], fmaf(y, w1[c], bb[c]));
                    acc[c] += fmaxf(h, 0.f);
                }
            }
#pragma unroll
            for (int c = 0; c < 16; c++) H[b][tm][cq + c] = acc[c] * (1.0f / 11.0f);
        }
    }
    __syncthreads();

    {
        int b  = tid >> 2;
        int tm = (tid >> 1) & 1;
        int ch = (tid & 1) * 32;
        float acc[32];
#pragma unroll
        for (int c = 0; c < 32; c++) acc[c] = 0.f;
        for (int k = 0; k < 64; k++) {
            float h = H[b][tm][k];
#pragma unroll
            for (int c = 0; c < 32; c++) acc[c] = fmaf(h, W2[k][ch + c], acc[c]);
        }
#pragma unroll
        for (int c = 0; c < 32; c++) O[tm * 64 + ch + c][b] = acc[c] + b_e2[ch + c];
    }
    __syncthreads();

    float* encT = enc_ws + (size_t)t * 128 * 1024 + bc * 64;
    for (int idx = tid; idx < 128 * 64; idx += 256) {
        int r = idx >> 6, b = idx & 63;
        encT[(size_t)r * 1024 + b] = O[r][b];
    }
    float* ptrT = ptr_ws + (size_t)t * 44 * 1024 + bc * 64;
    for (int idx = tid; idx < 44 * 64; idx += 256) {
        int j = idx >> 6, b = idx & 63;
        ptrT[(size_t)j * 1024 + b] = C[b][(j >> 1) * 4 + (j & 1)];
    }
}

// ---------------- custom grid barrier (device-scope atomics) ----------------
__device__ __forceinline__ void grid_barrier(unsigned* bar, unsigned* gen, unsigned my_gen) {
    __syncthreads();   // all block threads done (compiler drains vmcnt before s_barrier)
    if (threadIdx.x == 0) {
        unsigned arrived = __hip_atomic_fetch_add(bar, 1u, __ATOMIC_ACQ_REL, __HIP_MEMORY_SCOPE_AGENT);
        if (arrived == NBLK - 1) {
            __hip_atomic_store(bar, 0u, __ATOMIC_RELAXED, __HIP_MEMORY_SCOPE_AGENT);
            __hip_atomic_store(gen, my_gen + 1, __ATOMIC_RELEASE, __HIP_MEMORY_SCOPE_AGENT);
        } else {
            while (__hip_atomic_load(gen, __ATOMIC_ACQUIRE, __HIP_MEMORY_SCOPE_AGENT) == my_gen) {
                __builtin_amdgcn_s_sleep(1);
            }
        }
    }
    __syncthreads();
}

// ---------------- Persistent sequence kernel ----------------
// grid 256 (1 block/CU): bi = blockIdx.x&15 (64-batch tile), hj = blockIdx.x>>4 (16-hidden tile).
// hx exchange via device-scope (agent) atomic load/store — per-XCD L2s are not coherent.
__global__ __launch_bounds__(256, 1) void seq_kernel(
    const float* __restrict__ enc_ws, const float* __restrict__ ptr_ws,
    float* __restrict__ hxA, float* __restrict__ hxB,
    const float* __restrict__ W_ih, const float* __restrict__ b_ih,
    const float* __restrict__ W_hh, const float* __restrict__ b_hh,
    const float* __restrict__ WoT, const float* __restrict__ b_out,
    const float* __restrict__ pitch, float* __restrict__ d_out,
    unsigned* bar, unsigned* gen)
{
    __shared__ float X[KTOT][64];     // 110336 B
    __shared__ float U[2 * 4096];     // 32768 B: P scratch / W chunk dbuf / G gates
    __shared__ float Wo[8 * 256];     // 8192 B
    __shared__ float predL[64][2];    // 512 B

    int tid = threadIdx.x;
    int bi = blockIdx.x & 15, hj = blockIdx.x >> 4;
    int bg0 = bi * 64;

    // ---- hoisted: Wo columns ----
    for (int idx = tid; idx < 8 * 256; idx += 256) {
        int c = idx >> 8, k = idx & 255;
        int col = (c < 6) ? (hj * 6 + c) : (88 + (c - 6));
        Wo[idx] = (col < 90) ? WoT[col * 256 + k] : 0.f;
    }

    // ---- hoisted: W slice into registers ----
    float4 wreg[7][4];
#pragma unroll
    for (int ch = 0; ch < 7; ch++) {
#pragma unroll
        for (int i = 0; i < 4; i++) {
            int f4 = i * 256 + tid;
            int kr = f4 >> 4;
            int c4 = (f4 & 15) * 4;
            int k = ch * 64 + kr;
            int gcol = ((c4 >> 4) << 8) + hj * 16 + (c4 & 15);
            if (k < 175)       wreg[ch][i] = *(const float4*)&W_ih[(size_t)k * 1024 + gcol];
            else if (k < KTOT) wreg[ch][i] = *(const float4*)&W_hh[(size_t)(k - 175) * 1024 + gcol];
            else               wreg[ch][i] = make_float4(0.f, 0.f, 0.f, 0.f);
        }
    }

    // ---- hoisted: gate bias sums ----
    float bsum[4][4];
    {
        int hq = tid >> 6;
#pragma unroll
        for (int q = 0; q < 4; q++) {
            int gb = hj * 16 + hq * 4 + q;
#pragma unroll
            for (int g = 0; g < 4; g++)
                bsum[q][g] = b_ih[g * 256 + gb] + b_hh[g * 256 + gb];
        }
    }

    float c_reg[4] = {0.f, 0.f, 0.f, 0.f};
    unsigned bgen = 0;

    for (int t = 0; t <= SEQ; t++) {
        const float* hx_in = (t & 1) ? hxB : hxA;
        float* hx_out      = (t & 1) ? hxA : hxB;

        // ---- stage X ----
        if (t < SEQ) {
            const float* ptrT = ptr_ws + (size_t)t * 44 * 1024 + bg0;
            for (int idx = tid; idx < 44 * 16; idx += 256) {
                int r = idx >> 4, q = idx & 15;
                *(float4*)&X[r][q * 4] = *(const float4*)(ptrT + (size_t)r * 1024 + q * 4);
            }
            const float* encT = enc_ws + (size_t)t * 128 * 1024 + bg0;
            for (int idx = tid; idx < 128 * 16; idx += 256) {
                int r = idx >> 4, q = idx & 15;
                *(float4*)&X[44 + r][q * 4] = *(const float4*)(encT + (size_t)r * 1024 + q * 4);
            }
        }
        {
            // hx: device-coherent 64-bit atomic loads (bypass stale XCD L2/L1)
            const float* hxT = hx_in + bg0;
            for (int idx = tid; idx < 256 * 32; idx += 256) {
                int r = idx >> 5, q = idx & 31;
                unsigned long long v = __hip_atomic_load(
                    (const unsigned long long*)(hxT + (size_t)r * 1024 + q * 2),
                    __ATOMIC_RELAXED, __HIP_MEMORY_SCOPE_AGENT);
                float2 f2 = make_float2(__uint_as_float((unsigned)v),
                                        __uint_as_float((unsigned)(v >> 32)));
                *(float2*)&X[175 + r][q * 2] = f2;
            }
        }
        __syncthreads();

        // ---- pred_{t-1} + out_{t-1} = hx_{t-1} @ W_out cols ----
        {
            int b = tid & 63, kq = tid >> 6;
            float accO[8];
#pragma unroll
            for (int c = 0; c < 8; c++) accO[c] = 0.f;
            if (t > 0) {
                for (int k = kq * 64; k < kq * 64 + 64; k++) {
                    float xv = X[175 + k][b];
#pragma unroll
                    for (int c = 0; c < 8; c++) accO[c] = fmaf(xv, Wo[c * 256 + k], accO[c]);
                }
            }
            float* P = U;  // [4][64][8]
#pragma unroll
            for (int c = 0; c < 8; c++) P[(kq * 64 + b) * 8 + c] = accO[c];
        }
        __syncthreads();
        if (tid < 128) {
            int b = tid >> 1, hf = tid & 1;
            const float* P = U;
#pragma unroll
            for (int j = 0; j < 4; j++) {
                int c = hf * 4 + j;
                float s = P[(0 * 64 + b) * 8 + c] + P[(1 * 64 + b) * 8 + c] +
                          P[(2 * 64 + b) * 8 + c] + P[(3 * 64 + b) * 8 + c];
                int col = (c < 6) ? (hj * 6 + c) : (88 + (c - 6));
                if (t > 0 && col < 90) {
                    float v = (s + b_out[col]) * pitch[col & 1];
                    if (c < 6) d_out[((size_t)(bg0 + b) * SEQ + (t - 1)) * 90 + col] = v;
                    else predL[b][c - 6] = v;
                } else if (c >= 6) {
                    predL[b][c - 6] = 0.f;
                }
            }
        }
        __syncthreads();

        if (t < SEQ) {
            // ---- closest distance ----
            if (tid < 64) {
                int b = tid;
                float p0 = predL[b][0], p1 = predL[b][1];
                float m = 1e30f;
#pragma unroll
                for (int p = 0; p < 22; p++) {
                    float dx = p0 - X[2 * p][b];
                    float dy = p1 - X[2 * p + 1][b];
                    m = fminf(m, fmaf(dx, dx, dy * dy));
                }
                X[172][b] = sqrtf(m);
                X[173][b] = p0;
                X[174][b] = p1;
            }
            __syncthreads();

            // ---- GEMM: gates[64b x 64c] over K=431 ----
            int tb = tid & 15, tc = tid >> 4;
            float acc[4][4];
#pragma unroll
            for (int i = 0; i < 4; i++)
#pragma unroll
                for (int j = 0; j < 4; j++) acc[i][j] = 0.f;

            {
                float* Ub = U;
#pragma unroll
                for (int i = 0; i < 4; i++) {
                    int f4 = i * 256 + tid;
                    *(float4*)&Ub[(f4 >> 4) * 64 + (f4 & 15) * 4] = wreg[0][i];
                }
            }
            __syncthreads();
#pragma unroll
            for (int ch = 0; ch < 7; ch++) {
                const float* Wc = U + (ch & 1) * 4096;
                const float* Xc = &X[ch * 64][0];
                const int kend = (ch == 6) ? 47 : 64;
#pragma unroll 4
                for (int kr = 0; kr < kend; kr++) {
                    float4 xv4 = *(const float4*)(Xc + kr * 64 + tb * 4);
                    float4 wv4 = *(const float4*)(Wc + kr * 64 + tc * 4);
                    float xv[4] = {xv4.x, xv4.y, xv4.z, xv4.w};
                    float wv[4] = {wv4.x, wv4.y, wv4.z, wv4.w};
#pragma unroll
                    for (int i = 0; i < 4; i++)
#pragma unroll
                        for (int j = 0; j < 4; j++)
                            acc[i][j] = fmaf(xv[i], wv[j], acc[i][j]);
                }
                if (ch < 6) {
                    float* Ub = U + (((ch & 1) ^ 1) * 4096);
#pragma unroll
                    for (int i = 0; i < 4; i++) {
                        int f4 = i * 256 + tid;
                        *(float4*)&Ub[(f4 >> 4) * 64 + (f4 & 15) * 4] = wreg[ch + 1][i];
                    }
                }
                __syncthreads();
            }

            // ---- gates exchange + LSTM pointwise ----
            float* G = U;
#pragma unroll
            for (int i = 0; i < 4; i++)
#pragma unroll
                for (int j = 0; j < 4; j++)
                    G[(tc * 4 + j) * 64 + (tb * 4 + i)] = acc[i][j];
            __syncthreads();
            {
                int b = tid & 63;
#pragma unroll
                for (int q = 0; q < 4; q++) {
                    int hl = (tid >> 6) * 4 + q;
                    int gb = hj * 16 + hl;
                    float iv = G[(0  + hl) * 64 + b] + bsum[q][0];
                    float fv = G[(16 + hl) * 64 + b] + bsum[q][1];
                    float gv = G[(32 + hl) * 64 + b] + bsum[q][2];
                    float ov = G[(48 + hl) * 64 + b] + bsum[q][3];
                    float c_new = fmaf(sigmoidf_(fv), c_reg[q], sigmoidf_(iv) * tanhf(gv));
                    c_reg[q] = c_new;
                    // device-coherent store (write-through to coherence point)
                    __hip_atomic_store(hx_out + (size_t)gb * 1024 + bg0 + b,
                                       sigmoidf_(ov) * tanhf(c_new),
                                       __ATOMIC_RELAXED, __HIP_MEMORY_SCOPE_AGENT);
                }
            }
        }

        if (t != SEQ) {
            grid_barrier(bar, gen, bgen);
            bgen++;
        }
    }
}

// ---------------- Fallback per-step kernel (round-0 proven path) ----------------
__global__ __launch_bounds__(256) void step_kernel(
    int t,
    const float* __restrict__ enc_ws, const float* __restrict__ ptr_ws,
    const float* __restrict__ hx_in, float* __restrict__ hx_out, float* __restrict__ cx,
    const float* __restrict__ W_ih, const float* __restrict__ b_ih,
    const float* __restrict__ W_hh, const float* __restrict__ b_hh,
    const float* __restrict__ WoT, const float* __restrict__ b_out,
    const float* __restrict__ pitch, float* __restrict__ d_out)
{
    __shared__ float X[KTOT][64];
    __shared__ float U[2 * 4096];
    __shared__ float Wo[8 * 256];
    __shared__ float predL[64][2];

    int tid = threadIdx.x;
    int bi = blockIdx.x & 15, hj = blockIdx.x >> 4;
    int bg0 = bi * 64;

    if (t < SEQ) {
        const float* ptrT = ptr_ws + (size_t)t * 44 * 1024 + bg0;
        for (int idx = tid; idx < 44 * 16; idx += 256) {
            int r = idx >> 4, q = idx & 15;
            *(float4*)&X[r][q * 4] = *(const float4*)(ptrT + (size_t)r * 1024 + q * 4);
        }
        const float* encT = enc_ws + (size_t)t * 128 * 1024 + bg0;
        for (int idx = tid; idx < 128 * 16; idx += 256) {
            int r = idx >> 4, q = idx & 15;
            *(float4*)&X[44 + r][q * 4] = *(const float4*)(encT + (size_t)r * 1024 + q * 4);
        }
    }
    {
        const float* hxT = hx_in + bg0;
        for (int idx = tid; idx < 256 * 16; idx += 256) {
            int r = idx >> 4, q = idx & 15;
            *(float4*)&X[175 + r][q * 4] = *(const float4*)(hxT + (size_t)r * 1024 + q * 4);
        }
    }
    for (int idx = tid; idx < 8 * 256; idx += 256) {
        int c = idx >> 8, k = idx & 255;
        int col = (c < 6) ? (hj * 6 + c) : (88 + (c - 6));
        Wo[idx] = (col < 90) ? WoT[col * 256 + k] : 0.f;
    }
    __syncthreads();

    {
        int b = tid & 63, kq = tid >> 6;
        float accO[8];
#pragma unroll
        for (int c = 0; c < 8; c++) accO[c] = 0.f;
        if (t > 0) {
            for (int k = kq * 64; k < kq * 64 + 64; k++) {
                float xv = X[175 + k][b];
#pragma unroll
                for (int c = 0; c < 8; c++) accO[c] = fmaf(xv, Wo[c * 256 + k], accO[c]);
            }
        }
        float* P = U;
#pragma unroll
        for (int c = 0; c < 8; c++) P[(kq * 64 + b) * 8 + c] = accO[c];
    }
    __syncthreads();
    if (tid < 128) {
        int b = tid >> 1, hf = tid & 1;
        const float* P = U;
#pragma unroll
        for (int j = 0; j < 4; j++) {
            int c = hf * 4 + j;
            float s = P[(0 * 64 + b) * 8 + c] + P[(1 * 64 + b) * 8 + c] +
                      P[(2 * 64 + b) * 8 + c] + P[(3 * 64 + b) * 8 + c];
            int col = (c < 6) ? (hj * 6 + c) : (88 + (c - 6));
            if (t > 0 && col < 90) {
                float v = (s + b_out[col]) * pitch[col & 1];
                if (c < 6) d_out[((size_t)(bg0 + b) * SEQ + (t - 1)) * 90 + col] = v;
                else predL[b][c - 6] = v;
            } else if (c >= 6) {
                predL[b][c - 6] = 0.f;
            }
        }
    }
    __syncthreads();

    if (t < SEQ) {
        if (tid < 64) {
            int b = tid;
            float p0 = predL[b][0], p1 = predL[b][1];
            float m = 1e30f;
#pragma unroll
            for (int p = 0; p < 22; p++) {
                float dx = p0 - X[2 * p][b];
                float dy = p1 - X[2 * p + 1][b];
                m = fminf(m, fmaf(dx, dx, dy * dy));
            }
            X[172][b] = sqrtf(m);
            X[173][b] = p0;
            X[174][b] = p1;
        }
        __syncthreads();

        int tb = tid & 15, tc = tid >> 4;
        float acc[4][4];
#pragma unroll
        for (int i = 0; i < 4; i++)
#pragma unroll
            for (int j = 0; j < 4; j++) acc[i][j] = 0.f;

        float4 pre[4];
        auto loadW = [&](int ch) {
#pragma unroll
            for (int i = 0; i < 4; i++) {
                int f4 = i * 256 + tid;
                int kr = f4 >> 4;
                int c4 = (f4 & 15) * 4;
                int k = ch * 64 + kr;
                int gcol = ((c4 >> 4) << 8) + hj * 16 + (c4 & 15);
                if (k < 175)      pre[i] = *(const float4*)&W_ih[(size_t)k * 1024 + gcol];
                else if (k < KTOT) pre[i] = *(const float4*)&W_hh[(size_t)(k - 175) * 1024 + gcol];
                else              pre[i] = make_float4(0.f, 0.f, 0.f, 0.f);
            }
        };
        auto storeW = [&](int buf) {
            float* Ub = U + buf * 4096;
#pragma unroll
            for (int i = 0; i < 4; i++) {
                int f4 = i * 256 + tid;
                int kr = f4 >> 4;
                int c4 = (f4 & 15) * 4;
                *(float4*)&Ub[kr * 64 + c4] = pre[i];
            }
        };
        loadW(0); storeW(0);
        __syncthreads();
        for (int ch = 0; ch < 7; ch++) {
            if (ch < 6) loadW(ch + 1);
            const float* Wc = U + (ch & 1) * 4096;
            const float* Xc = &X[ch * 64][0];
            int kend = (ch == 6) ? 47 : 64;
#pragma unroll 4
            for (int kr = 0; kr < kend; kr++) {
                float4 xv4 = *(const float4*)(Xc + kr * 64 + tb * 4);
                float4 wv4 = *(const float4*)(Wc + kr * 64 + tc * 4);
                float xv[4] = {xv4.x, xv4.y, xv4.z, xv4.w};
                float wv[4] = {wv4.x, wv4.y, wv4.z, wv4.w};
#pragma unroll
                for (int i = 0; i < 4; i++)
#pragma unroll
                    for (int j = 0; j < 4; j++)
                        acc[i][j] = fmaf(xv[i], wv[j], acc[i][j]);
            }
            if (ch < 6) storeW((ch & 1) ^ 1);
            __syncthreads();
        }

        float* G = U;
#pragma unroll
        for (int i = 0; i < 4; i++)
#pragma unroll
            for (int j = 0; j < 4; j++)
                G[(tc * 4 + j) * 64 + (tb * 4 + i)] = acc[i][j];
        __syncthreads();
        {
            int b = tid & 63, hq = tid >> 6;
#pragma unroll
            for (int q = 0; q < 4; q++) {
                int hl = hq * 4 + q;
                int gb = hj * 16 + hl;
                float iv = G[(0 + hl) * 64 + b] + b_ih[gb]       + b_hh[gb];
                float fv = G[(16 + hl) * 64 + b] + b_ih[256 + gb] + b_hh[256 + gb];
                float gv = G[(32 + hl) * 64 + b] + b_ih[512 + gb] + b_hh[512 + gb];
                float ov = G[(48 + hl) * 64 + b] + b_ih[768 + gb] + b_hh[768 + gb];
                size_t cidx = (size_t)gb * 1024 + bg0 + b;
                float c_old = cx[cidx];
                float c_new = fmaf(sigmoidf_(fv), c_old, sigmoidf_(iv) * tanhf(gv));
                cx[cidx] = c_new;
                hx_out[cidx] = sigmoidf_(ov) * tanhf(c_new);
            }
        }
    }
}

extern "C" void kernel_launch(void* const* d_in, const int* in_sizes, int n_in,
                              void* d_out, int out_size, void* d_ws, size_t ws_size,
                              hipStream_t stream) {
    const float* coords = (const float*)d_in[0];
    const float* pitch  = (const float*)d_in[1];
    const float* W_e1   = (const float*)d_in[2];
    const float* b_e1   = (const float*)d_in[3];
    const float* W_e2   = (const float*)d_in[4];
    const float* b_e2   = (const float*)d_in[5];
    const float* W_ih   = (const float*)d_in[6];
    const float* b_ih   = (const float*)d_in[7];
    const float* W_hh   = (const float*)d_in[8];
    const float* b_hh   = (const float*)d_in[9];
    const float* W_out  = (const float*)d_in[10];
    const float* b_out  = (const float*)d_in[11];
    float* out = (float*)d_out;
    float* ws  = (float*)d_ws;

    // ws layout (floats):
    float* hxA    = ws;                    // 262144
    float* cxb    = ws + 262144;           // 262144 (fallback cx; first 64 floats double as barrier vars on coop path)
    float* hxB    = ws + 524288;           // 262144
    float* WoT    = ws + 786432;           // 23040
    float* ptr_ws = ws + 809472;           // 200*44*1024   = 9011200
    float* enc_ws = ws + 9820672;          // 200*128*1024  = 26214400

    unsigned* bar = (unsigned*)(ws + 262144);       // zeroed below
    unsigned* gen = (unsigned*)(ws + 262144 + 32);  // separate 128B line

    // zero hxA + cx/barrier region (poisoned 0xAA by harness)
    hipMemsetAsync(ws, 0, (size_t)2 * 262144 * sizeof(float), stream);

    transpose_wout<<<90, 256, 0, stream>>>(W_out, WoT);
    enc_kernel<<<SEQ * 16, 256, 0, stream>>>(coords, W_e1, b_e1, W_e2, b_e2, enc_ws, ptr_ws);

    void* args[] = { (void*)&enc_ws, (void*)&ptr_ws, (void*)&hxA, (void*)&hxB,
                     (void*)&W_ih, (void*)&b_ih, (void*)&W_hh, (void*)&b_hh,
                     (void*)&WoT, (void*)&b_out, (void*)&pitch, (void*)&out,
                     (void*)&bar, (void*)&gen };
    hipError_t e = hipLaunchCooperativeKernel((void*)seq_kernel, dim3(NBLK), dim3(256),
                                              args, 0, stream);
    if (e != hipSuccess) {
        // fallback: proven per-step path
        for (int t = 0; t <= SEQ; t++) {
            const float* hin = (t & 1) ? hxB : hxA;
            float* hout      = (t & 1) ? hxA : hxB;
            step_kernel<<<256, 256, 0, stream>>>(t, enc_ws, ptr_ws, hin, hout, cxb,
                                                 W_ih, b_ih, W_hh, b_hh, WoT, b_out, pitch, out);
        }
    }
}

// Round 3
// 9036.369 us; speedup vs baseline: 1.3023x; 1.3023x over previous
//
#include <hip/hip_runtime.h>
#include <math.h>

#define SEQ 200
#define KTOT 431   // 44 ptr + 128 enc + 1 closest + 2 pred + 256 hx

__device__ __forceinline__ float sigmoidf_(float x) { return 1.0f / (1.0f + __expf(-x)); }

// ---------------- W_out transpose: WoT[90][256] ----------------
__global__ void transpose_wout(const float* __restrict__ W_out, float* __restrict__ WoT) {
    int c = blockIdx.x;      // 0..89
    int k = threadIdx.x;     // 0..255
    WoT[c * 256 + k] = W_out[k * 90 + c];
}

// ---------------- Encoder + ptr transpose ----------------
// grid: SEQ*16 blocks (t, batch-chunk of 64), 256 threads
__global__ __launch_bounds__(256) void enc_kernel(
    const float* __restrict__ coords,
    const float* __restrict__ W_e1, const float* __restrict__ b_e1,
    const float* __restrict__ W_e2, const float* __restrict__ b_e2,
    float* __restrict__ enc_ws, float* __restrict__ ptr_ws)
{
    __shared__ float C[64][89];       // coords rows (pad 89 to spread banks)
    __shared__ float H[64][2][65];    // h_mean, padded
    __shared__ float W2[64][64];
    __shared__ float O[128][64];

    int t  = blockIdx.x >> 4;
    int bc = blockIdx.x & 15;
    int tid = threadIdx.x;

    for (int idx = tid; idx < 64 * 88; idx += 256) {
        int bl = idx / 88, j = idx - bl * 88;
        C[bl][j] = coords[((size_t)(bc * 64 + bl) * SEQ + t) * 88 + j];
    }
    for (int idx = tid; idx < 64 * 64; idx += 256)
        W2[idx >> 6][idx & 63] = W_e2[idx];
    __syncthreads();

    // phase A: per-team mean of relu(pts @ W_e1 + b_e1)
    {
        int b  = tid >> 2;
        int cq = (tid & 3) * 16;
        float w0[16], w1[16], bb[16];
#pragma unroll
        for (int c = 0; c < 16; c++) { w0[c] = W_e1[cq + c]; w1[c] = W_e1[64 + cq + c]; bb[c] = b_e1[cq + c]; }
        for (int tm = 0; tm < 2; tm++) {
            float acc[16];
#pragma unroll
            for (int c = 0; c < 16; c++) acc[c] = 0.f;
            for (int p = 0; p < 11; p++) {
                float x = C[b][(tm * 11 + p) * 4];
                float y = C[b][(tm * 11 + p) * 4 + 1];
#pragma unroll
                for (int c = 0; c < 16; c++) {
                    float h = fmaf(x, w0[c], fmaf(y, w1[c], bb[c]));
                    acc[c] += fmaxf(h, 0.f);
                }
            }
#pragma unroll
            for (int c = 0; c < 16; c++) H[b][tm][cq + c] = acc[c] * (1.0f / 11.0f);
        }
    }
    __syncthreads();

    // phase B: out = h_mean @ W_e2 + b_e2
    {
        int b  = tid >> 2;
        int tm = (tid >> 1) & 1;
        int ch = (tid & 1) * 32;
        float acc[32];
#pragma unroll
        for (int c = 0; c < 32; c++) acc[c] = 0.f;
        for (int k = 0; k < 64; k++) {
            float h = H[b][tm][k];
#pragma unroll
            for (int c = 0; c < 32; c++) acc[c] = fmaf(h, W2[k][ch + c], acc[c]);
        }
#pragma unroll
        for (int c = 0; c < 32; c++) O[tm * 64 + ch + c][b] = acc[c] + b_e2[ch + c];
    }
    __syncthreads();

    float* encT = enc_ws + (size_t)t * 128 * 1024 + bc * 64;
    for (int idx = tid; idx < 128 * 64; idx += 256) {
        int r = idx >> 6, b = idx & 63;
        encT[(size_t)r * 1024 + b] = O[r][b];
    }
    float* ptrT = ptr_ws + (size_t)t * 44 * 1024 + bc * 64;
    for (int idx = tid; idx < 44 * 64; idx += 256) {
        int j = idx >> 6, b = idx & 63;
        ptrT[(size_t)j * 1024 + b] = C[b][(j >> 1) * 4 + (j & 1)];
    }
}

// ---------------- Per-step kernel ----------------
// grid 256: bi = blockIdx.x&15 (64-batch tile), hj = blockIdx.x>>4 (16-hidden tile)
// t in [0, SEQ]: computes out_{t-1}+pred_{t-1} from hx_in, then (t<SEQ) gates+LSTM.
// W is NOT staged through LDS: each wave's W read per k-row is one 64-B L2 line
// (431 lines = 27.6 KB, L1-resident) -> GEMM LDS traffic halves, 7 barriers vanish.
__global__ __launch_bounds__(256) void step_kernel(
    int t,
    const float* __restrict__ enc_ws, const float* __restrict__ ptr_ws,
    const float* __restrict__ hx_in, float* __restrict__ hx_out, float* __restrict__ cx,
    const float* __restrict__ W_ih, const float* __restrict__ b_ih,
    const float* __restrict__ W_hh, const float* __restrict__ b_hh,
    const float* __restrict__ WoT, const float* __restrict__ b_out,
    const float* __restrict__ pitch, float* __restrict__ d_out)
{
    __shared__ float X[KTOT][64];     // 110336 B
    __shared__ float U[4096];         // 16384 B: P scratch / G gates
    __shared__ float Wo[8 * 256];     // 8192 B
    __shared__ float predL[64][2];    // 512 B

    int tid = threadIdx.x;
    int bi = blockIdx.x & 15, hj = blockIdx.x >> 4;
    int bg0 = bi * 64;

    // ---- stage X ----
    if (t < SEQ) {
        const float* ptrT = ptr_ws + (size_t)t * 44 * 1024 + bg0;
        for (int idx = tid; idx < 44 * 16; idx += 256) {
            int r = idx >> 4, q = idx & 15;
            *(float4*)&X[r][q * 4] = *(const float4*)(ptrT + (size_t)r * 1024 + q * 4);
        }
        const float* encT = enc_ws + (size_t)t * 128 * 1024 + bg0;
        for (int idx = tid; idx < 128 * 16; idx += 256) {
            int r = idx >> 4, q = idx & 15;
            *(float4*)&X[44 + r][q * 4] = *(const float4*)(encT + (size_t)r * 1024 + q * 4);
        }
    }
    {
        const float* hxT = hx_in + bg0;
        for (int idx = tid; idx < 256 * 16; idx += 256) {
            int r = idx >> 4, q = idx & 15;
            *(float4*)&X[175 + r][q * 4] = *(const float4*)(hxT + (size_t)r * 1024 + q * 4);
        }
    }
    // stage Wo: up to 8 W_out columns (6 out-slice + 2 pred)
    for (int idx = tid; idx < 8 * 256; idx += 256) {
        int c = idx >> 8, k = idx & 255;
        int col = (c < 6) ? (hj * 6 + c) : (88 + (c - 6));
        Wo[idx] = (col < 90) ? WoT[col * 256 + k] : 0.f;
    }
    __syncthreads();

    // ---- pred_{t-1} + out_{t-1} = hx_{t-1} @ W_out cols ----
    {
        int b = tid & 63, kq = tid >> 6;
        float accO[8];
#pragma unroll
        for (int c = 0; c < 8; c++) accO[c] = 0.f;
        if (t > 0) {
            for (int k = kq * 64; k < kq * 64 + 64; k++) {
                float xv = X[175 + k][b];
#pragma unroll
                for (int c = 0; c < 8; c++) accO[c] = fmaf(xv, Wo[c * 256 + k], accO[c]);
            }
        }
        float* P = U;  // [4][64][8]
#pragma unroll
        for (int c = 0; c < 8; c++) P[(kq * 64 + b) * 8 + c] = accO[c];
    }
    __syncthreads();
    if (tid < 128) {
        int b = tid >> 1, hf = tid & 1;
        const float* P = U;
#pragma unroll
        for (int j = 0; j < 4; j++) {
            int c = hf * 4 + j;
            float s = P[(0 * 64 + b) * 8 + c] + P[(1 * 64 + b) * 8 + c] +
                      P[(2 * 64 + b) * 8 + c] + P[(3 * 64 + b) * 8 + c];
            int col = (c < 6) ? (hj * 6 + c) : (88 + (c - 6));
            if (t > 0 && col < 90) {
                float v = (s + b_out[col]) * pitch[col & 1];
                if (c < 6) d_out[((size_t)(bg0 + b) * SEQ + (t - 1)) * 90 + col] = v;
                else predL[b][c - 6] = v;
            } else if (c >= 6) {
                predL[b][c - 6] = 0.f;
            }
        }
    }
    __syncthreads();

    if (t < SEQ) {
        // ---- closest distance; fill X rows 172..174 ----
        if (tid < 64) {
            int b = tid;
            float p0 = predL[b][0], p1 = predL[b][1];
            float m = 1e30f;
#pragma unroll
            for (int p = 0; p < 22; p++) {
                float dx = p0 - X[2 * p][b];
                float dy = p1 - X[2 * p + 1][b];
                m = fminf(m, fmaf(dx, dx, dy * dy));
            }
            X[172][b] = sqrtf(m);
            X[173][b] = p0;
            X[174][b] = p1;
        }
        __syncthreads();

        // ---- GEMM: gates[64b x 64c] over K=431; X from LDS, W direct from global ----
        int tb = tid & 15, tc = tid >> 4;
        // gcol: same column mapping as before (c4 = tc*4):
        int gcol = ((tc >> 2) << 8) + hj * 16 + ((tc & 3) << 2);
        float acc[4][4];
#pragma unroll
        for (int i = 0; i < 4; i++)
#pragma unroll
            for (int j = 0; j < 4; j++) acc[i][j] = 0.f;

        const float* Wih_c = W_ih + gcol;
        const float* Whh_c = W_hh + gcol;

        // part 1: k in [0, 175)  (W_ih rows)
#pragma unroll 4
        for (int kr = 0; kr < 175; kr++) {
            float4 xv4 = *(const float4*)&X[kr][tb * 4];
            float4 wv4 = *(const float4*)(Wih_c + (size_t)kr * 1024);
            float xv[4] = {xv4.x, xv4.y, xv4.z, xv4.w};
            float wv[4] = {wv4.x, wv4.y, wv4.z, wv4.w};
#pragma unroll
            for (int i = 0; i < 4; i++)
#pragma unroll
                for (int j = 0; j < 4; j++)
                    acc[i][j] = fmaf(xv[i], wv[j], acc[i][j]);
        }
        // part 2: k in [175, 431)  (W_hh rows)
#pragma unroll 4
        for (int kr = 0; kr < 256; kr++) {
            float4 xv4 = *(const float4*)&X[175 + kr][tb * 4];
            float4 wv4 = *(const float4*)(Whh_c + (size_t)kr * 1024);
            float xv[4] = {xv4.x, xv4.y, xv4.z, xv4.w};
            float wv[4] = {wv4.x, wv4.y, wv4.z, wv4.w};
#pragma unroll
            for (int i = 0; i < 4; i++)
#pragma unroll
                for (int j = 0; j < 4; j++)
                    acc[i][j] = fmaf(xv[i], wv[j], acc[i][j]);
        }

        // ---- exchange gates through LDS, LSTM pointwise ----
        float* G = U;  // [64 c_local][64 b]
        __syncthreads();
#pragma unroll
        for (int i = 0; i < 4; i++)
#pragma unroll
            for (int j = 0; j < 4; j++)
                G[(tc * 4 + j) * 64 + (tb * 4 + i)] = acc[i][j];
        __syncthreads();
        {
            int b = tid & 63, hq = tid >> 6;
#pragma unroll
            for (int q = 0; q < 4; q++) {
                int hl = hq * 4 + q;              // 0..15
                int gb = hj * 16 + hl;            // global hidden index
                float iv = G[(0 + hl) * 64 + b] + b_ih[gb]       + b_hh[gb];
                float fv = G[(16 + hl) * 64 + b] + b_ih[256 + gb] + b_hh[256 + gb];
                float gv = G[(32 + hl) * 64 + b] + b_ih[512 + gb] + b_hh[512 + gb];
                float ov = G[(48 + hl) * 64 + b] + b_ih[768 + gb] + b_hh[768 + gb];
                size_t cidx = (size_t)gb * 1024 + bg0 + b;
                float c_old = cx[cidx];
                float c_new = fmaf(sigmoidf_(fv), c_old, sigmoidf_(iv) * tanhf(gv));
                cx[cidx] = c_new;
                hx_out[cidx] = sigmoidf_(ov) * tanhf(c_new);
            }
        }
    }
}

extern "C" void kernel_launch(void* const* d_in, const int* in_sizes, int n_in,
                              void* d_out, int out_size, void* d_ws, size_t ws_size,
                              hipStream_t stream) {
    const float* coords = (const float*)d_in[0];
    const float* pitch  = (const float*)d_in[1];
    const float* W_e1   = (const float*)d_in[2];
    const float* b_e1   = (const float*)d_in[3];
    const float* W_e2   = (const float*)d_in[4];
    const float* b_e2   = (const float*)d_in[5];
    const float* W_ih   = (const float*)d_in[6];
    const float* b_ih   = (const float*)d_in[7];
    const float* W_hh   = (const float*)d_in[8];
    const float* b_hh   = (const float*)d_in[9];
    const float* W_out  = (const float*)d_in[10];
    const float* b_out  = (const float*)d_in[11];
    float* out = (float*)d_out;
    float* ws  = (float*)d_ws;

    // ws layout (floats):
    float* hxA    = ws;                    // 262144
    float* cxb    = ws + 262144;           // 262144
    float* hxB    = ws + 524288;           // 262144
    float* WoT    = ws + 786432;           // 23040
    float* ptr_ws = ws + 809472;           // 200*44*1024   = 9011200
    float* enc_ws = ws + 9820672;          // 200*128*1024  = 26214400

    // zero hxA + cx (poisoned 0xAA by harness)
    hipMemsetAsync(ws, 0, (size_t)2 * 262144 * sizeof(float), stream);

    transpose_wout<<<90, 256, 0, stream>>>(W_out, WoT);
    enc_kernel<<<SEQ * 16, 256, 0, stream>>>(coords, W_e1, b_e1, W_e2, b_e2, enc_ws, ptr_ws);

    for (int t = 0; t <= SEQ; t++) {
        const float* hin = (t & 1) ? hxB : hxA;
        float* hout      = (t & 1) ? hxA : hxB;
        step_kernel<<<256, 256, 0, stream>>>(t, enc_ws, ptr_ws, hin, hout, cxb,
                                             W_ih, b_ih, W_hh, b_hh, WoT, b_out, pitch, out);
    }
}

// Round 4
// 3667.138 us; speedup vs baseline: 3.2092x; 2.4641x over previous
//
#include <hip/hip_runtime.h>
#include <math.h>

#define SEQ 200

typedef float f32x4 __attribute__((ext_vector_type(4)));
typedef short bf16x8 __attribute__((ext_vector_type(8)));

__device__ __forceinline__ float sigmoidf_(float x) { return 1.0f / (1.0f + __expf(-x)); }

__device__ __forceinline__ unsigned short bf16_rn(float v) {
    unsigned x = __float_as_uint(v);
    unsigned r = x + 0x7FFFu + ((x >> 16) & 1u);
    return (unsigned short)(r >> 16);
}
__device__ __forceinline__ float bf16_to_f(unsigned short h) {
    return __uint_as_float(((unsigned)h) << 16);
}
__device__ __forceinline__ void cvt_hl(float v, unsigned short& h, unsigned short& l) {
    h = bf16_rn(v);
    l = bf16_rn(v - bf16_to_f(h));
}

// ---------------- W_out transpose: WoT[90][256] ----------------
__global__ void transpose_wout(const float* __restrict__ W_out, float* __restrict__ WoT) {
    int c = blockIdx.x;      // 0..89
    int k = threadIdx.x;     // 0..255
    WoT[c * 256 + k] = W_out[k * 90 + c];
}

// ---------------- Wt prep: Wt_h/Wt_l[1024 rc][448 k] bf16 ----------------
// rc = hj*128 + lc; gcol = (lc>>5)*256 + hj*32 + (lc&31). k: 0-174 W_ih, 175 zero,
// 176-431 W_hh, 432-447 zero.
__global__ void prep_wt(const float* __restrict__ W_ih, const float* __restrict__ W_hh,
                        unsigned short* __restrict__ Wt_h, unsigned short* __restrict__ Wt_l) {
    int rc = blockIdx.x;
    int hj = rc >> 7, lc = rc & 127;
    int gcol = (lc >> 5) * 256 + hj * 32 + (lc & 31);
    for (int k = threadIdx.x; k < 448; k += 256) {
        float v = 0.f;
        if (k < 175) v = W_ih[(size_t)k * 1024 + gcol];
        else if (k >= 176 && k < 432) v = W_hh[(size_t)(k - 176) * 1024 + gcol];
        unsigned short h, l; cvt_hl(v, h, l);
        Wt_h[(size_t)rc * 448 + k] = h;
        Wt_l[(size_t)rc * 448 + k] = l;
    }
}

// ---------------- Encoder -> xin_h[t][b][176] bf16 ----------------
// k: 0-43 ptr (coords strided), 44-171 enc, 172-175 zero placeholders.
__global__ __launch_bounds__(256) void enc_kernel(
    const float* __restrict__ coords,
    const float* __restrict__ W_e1, const float* __restrict__ b_e1,
    const float* __restrict__ W_e2, const float* __restrict__ b_e2,
    unsigned short* __restrict__ xin_h)
{
    __shared__ float C[64][89];
    __shared__ float H[64][2][65];
    __shared__ float W2[64][64];
    __shared__ float O[128][64];

    int t  = blockIdx.x >> 4;
    int bc = blockIdx.x & 15;
    int tid = threadIdx.x;

    for (int idx = tid; idx < 64 * 88; idx += 256) {
        int bl = idx / 88, j = idx - bl * 88;
        C[bl][j] = coords[((size_t)(bc * 64 + bl) * SEQ + t) * 88 + j];
    }
    for (int idx = tid; idx < 64 * 64; idx += 256)
        W2[idx >> 6][idx & 63] = W_e2[idx];
    __syncthreads();

    {
        int b  = tid >> 2;
        int cq = (tid & 3) * 16;
        float w0[16], w1[16], bb[16];
#pragma unroll
        for (int c = 0; c < 16; c++) { w0[c] = W_e1[cq + c]; w1[c] = W_e1[64 + cq + c]; bb[c] = b_e1[cq + c]; }
        for (int tm = 0; tm < 2; tm++) {
            float acc[16];
#pragma unroll
            for (int c = 0; c < 16; c++) acc[c] = 0.f;
            for (int p = 0; p < 11; p++) {
                float x = C[b][(tm * 11 + p) * 4];
                float y = C[b][(tm * 11 + p) * 4 + 1];
#pragma unroll
                for (int c = 0; c < 16; c++) {
                    float h = fmaf(x, w0[c], fmaf(y, w1[c], bb[c]));
                    acc[c] += fmaxf(h, 0.f);
                }
            }
#pragma unroll
            for (int c = 0; c < 16; c++) H[b][tm][cq + c] = acc[c] * (1.0f / 11.0f);
        }
    }
    __syncthreads();

    {
        int b  = tid >> 2;
        int tm = (tid >> 1) & 1;
        int ch = (tid & 1) * 32;
        float acc[32];
#pragma unroll
        for (int c = 0; c < 32; c++) acc[c] = 0.f;
        for (int k = 0; k < 64; k++) {
            float h = H[b][tm][k];
#pragma unroll
            for (int c = 0; c < 32; c++) acc[c] = fmaf(h, W2[k][ch + c], acc[c]);
        }
#pragma unroll
        for (int c = 0; c < 32; c++) O[tm * 64 + ch + c][b] = acc[c] + b_e2[ch + c];
    }
    __syncthreads();

    unsigned short* xrow = xin_h + ((size_t)t * 1024 + bc * 64) * 176;
    for (int idx = tid; idx < 64 * 22; idx += 256) {
        int bl = idx / 22, oct = idx - bl * 22;
        unsigned short hs[8];
#pragma unroll
        for (int e = 0; e < 8; e++) {
            int k = oct * 8 + e;
            float v;
            if (k < 44)       v = C[bl][(k >> 1) * 4 + (k & 1)];
            else if (k < 172) v = O[k - 44][bl];
            else              v = 0.f;
            hs[e] = bf16_rn(v);
        }
        uint4 pk;
        pk.x = (unsigned)hs[0] | ((unsigned)hs[1] << 16);
        pk.y = (unsigned)hs[2] | ((unsigned)hs[3] << 16);
        pk.z = (unsigned)hs[4] | ((unsigned)hs[5] << 16);
        pk.w = (unsigned)hs[6] | ((unsigned)hs[7] << 16);
        *(uint4*)(xrow + (size_t)bl * 176 + oct * 8) = pk;
    }
}

// ---------------- Per-step kernel (MFMA) ----------------
// grid 256: bi = blockIdx.x&31 (32-batch tile), hj = blockIdx.x>>5 (128-gatecol tile).
// gates GEMM: D[32b x 128c] over K=448, mfma_f32_16x16x32_bf16, split hi/lo:
//   acc += Ah*Bh + Ah*Bl + Al*Bh   (Al nonzero only on hx rows 176..431)
__global__ __launch_bounds__(256) void step_kernel(
    int t,
    const unsigned short* __restrict__ xin_h,
    const unsigned short* __restrict__ hxh_in, const unsigned short* __restrict__ hxl_in,
    unsigned short* __restrict__ hxh_out, unsigned short* __restrict__ hxl_out,
    const float* __restrict__ hx_in, float* __restrict__ hx_out, float* __restrict__ cx,
    const unsigned short* __restrict__ Wt_h, const unsigned short* __restrict__ Wt_l,
    const float* __restrict__ b_ih, const float* __restrict__ b_hh,
    const float* __restrict__ WoT, const float* __restrict__ b_out,
    const float* __restrict__ pitch, float* __restrict__ d_out)
{
    __shared__ unsigned short AH[32 * 456];        // 29184 B  (456 = 448 + 8 pad)
    __shared__ unsigned short AL[32 * 456];        // 29184 B
    __shared__ unsigned short BB[2][2][128 * 40];  // 40960 B  [buf][h/l][c*40 + k]
    __shared__ float U[128 * 33];                  // 16896 B  P scratch / G gates
    __shared__ float Wo[14 * 256];                 // 14336 B
    __shared__ float predL[32][2];                 // 256 B

    int tid = threadIdx.x;
    int bi = blockIdx.x & 31, hj = blockIdx.x >> 5;
    int bg0 = bi * 32;

    // ---- stage ----
    if (t < SEQ) {
        const unsigned short* xr = xin_h + ((size_t)t * 1024 + bg0) * 176;
        for (int idx = tid; idx < 32 * 22; idx += 256) {         // xin rows 0..175
            int b = idx / 22, oct = idx - b * 22;
            *(uint4*)&AH[b * 456 + oct * 8] = *(const uint4*)(xr + (size_t)b * 176 + oct * 8);
            *(uint4*)&AL[b * 456 + oct * 8] = make_uint4(0, 0, 0, 0);
        }
        for (int idx = tid; idx < 32 * 32; idx += 256) {         // hx rows 176..431
            int b = idx >> 5, oct = idx & 31;
            *(uint4*)&AH[b * 456 + 176 + oct * 8] =
                *(const uint4*)(hxh_in + (size_t)(bg0 + b) * 256 + oct * 8);
            *(uint4*)&AL[b * 456 + 176 + oct * 8] =
                *(const uint4*)(hxl_in + (size_t)(bg0 + b) * 256 + oct * 8);
        }
        for (int idx = tid; idx < 32 * 2; idx += 256) {          // zero rows 432..447
            int b = idx >> 1, oct = idx & 1;
            *(uint4*)&AH[b * 456 + 432 + oct * 8] = make_uint4(0, 0, 0, 0);
            *(uint4*)&AL[b * 456 + 432 + oct * 8] = make_uint4(0, 0, 0, 0);
        }
        // B chunk ks=0
        const unsigned short* wbh = Wt_h + (size_t)(hj * 128) * 448;
        const unsigned short* wbl = Wt_l + (size_t)(hj * 128) * 448;
        for (int idx = tid; idx < 512; idx += 256) {
            int c = idx >> 2, oct = idx & 3;
            *(uint4*)&BB[0][0][c * 40 + oct * 8] = *(const uint4*)(wbh + (size_t)c * 448 + oct * 8);
            *(uint4*)&BB[0][1][c * 40 + oct * 8] = *(const uint4*)(wbl + (size_t)c * 448 + oct * 8);
        }
    }
    for (int idx = tid; idx < 14 * 256; idx += 256) {
        int c = idx >> 8, k = idx & 255;
        int col = (c < 12) ? (hj * 12 + c) : (88 + (c - 12));
        Wo[idx] = (col < 90) ? WoT[col * 256 + k] : 0.f;
    }
    __syncthreads();

    // ---- out_{t-1} + pred_{t-1} = hx_{t-1}(fp32, global) @ Wo ----
    {
        int b = tid & 31, kq = tid >> 5;     // kq 0..7
        float accO[14];
#pragma unroll
        for (int c = 0; c < 14; c++) accO[c] = 0.f;
        if (t > 0) {
#pragma unroll 4
            for (int k = 0; k < 32; k++) {
                float xv = hx_in[(size_t)(kq * 32 + k) * 1024 + bg0 + b];
#pragma unroll
                for (int c = 0; c < 14; c++) accO[c] = fmaf(xv, Wo[c * 256 + kq * 32 + k], accO[c]);
            }
        }
        float* P = U;   // [8][32][14]
#pragma unroll
        for (int c = 0; c < 14; c++) P[(kq * 32 + b) * 14 + c] = accO[c];
    }
    __syncthreads();
    for (int idx = tid; idx < 448; idx += 256) {
        int b = idx / 14, c = idx - b * 14;
        float s = 0.f;
#pragma unroll
        for (int kq = 0; kq < 8; kq++) s += U[(kq * 32 + b) * 14 + c];
        int col = (c < 12) ? (hj * 12 + c) : (76 + c);
        if (col < 90) {
            if (t > 0) {
                float v = (s + b_out[col]) * pitch[col & 1];
                if (c < 12) d_out[((size_t)(bg0 + b) * SEQ + (t - 1)) * 90 + col] = v;
                else predL[b][c - 12] = v;
            } else if (c >= 12) {
                predL[b][c - 12] = 0.f;
            }
        }
    }
    __syncthreads();

    if (t < SEQ) {
        // ---- closest distance; fill A rows 172..174 ----
        if (tid < 32) {
            int b = tid;
            float p0 = predL[b][0], p1 = predL[b][1];
            float m = 1e30f;
#pragma unroll
            for (int p = 0; p < 22; p++) {
                float px = bf16_to_f(AH[b * 456 + 2 * p]);
                float py = bf16_to_f(AH[b * 456 + 2 * p + 1]);
                float dx = p0 - px, dy = p1 - py;
                m = fminf(m, fmaf(dx, dx, dy * dy));
            }
            unsigned short h, l;
            cvt_hl(sqrtf(m), h, l); AH[b * 456 + 172] = h; AL[b * 456 + 172] = l;
            cvt_hl(p0, h, l);       AH[b * 456 + 173] = h; AL[b * 456 + 173] = l;
            cvt_hl(p1, h, l);       AH[b * 456 + 174] = h; AL[b * 456 + 174] = l;
        }
        __syncthreads();

        // ---- MFMA K-loop: 14 steps of K=32, B double-buffered ----
        int l = tid & 63, w = tid >> 6;
        int lr = l & 15, qa = l >> 4;
        const unsigned short* wbh = Wt_h + (size_t)(hj * 128) * 448;
        const unsigned short* wbl = Wt_l + (size_t)(hj * 128) * 448;

        f32x4 acc[2][2];
#pragma unroll
        for (int ct = 0; ct < 2; ct++)
#pragma unroll
            for (int mt = 0; mt < 2; mt++) acc[ct][mt] = (f32x4){0.f, 0.f, 0.f, 0.f};

        uint4 bregH[2], bregL[2];
        for (int ks = 0; ks < 14; ks++) {
            int cur = ks & 1;
            if (ks < 13) {
                int ko = (ks + 1) * 32;
#pragma unroll
                for (int it = 0; it < 2; it++) {
                    int idx = tid + it * 256;
                    int c = idx >> 2, oct = idx & 3;
                    bregH[it] = *(const uint4*)(wbh + (size_t)c * 448 + ko + oct * 8);
                    bregL[it] = *(const uint4*)(wbl + (size_t)c * 448 + ko + oct * 8);
                }
            }
            bf16x8 ah[2], al[2], bh[2], bl[2];
#pragma unroll
            for (int mt = 0; mt < 2; mt++) {
                ah[mt] = *(const bf16x8*)&AH[(mt * 16 + lr) * 456 + ks * 32 + qa * 8];
                al[mt] = *(const bf16x8*)&AL[(mt * 16 + lr) * 456 + ks * 32 + qa * 8];
            }
#pragma unroll
            for (int ct = 0; ct < 2; ct++) {
                bh[ct] = *(const bf16x8*)&BB[cur][0][(w * 32 + ct * 16 + lr) * 40 + qa * 8];
                bl[ct] = *(const bf16x8*)&BB[cur][1][(w * 32 + ct * 16 + lr) * 40 + qa * 8];
            }
#pragma unroll
            for (int ct = 0; ct < 2; ct++)
#pragma unroll
                for (int mt = 0; mt < 2; mt++) {
                    acc[ct][mt] = __builtin_amdgcn_mfma_f32_16x16x32_bf16(ah[mt], bh[ct], acc[ct][mt], 0, 0, 0);
                    acc[ct][mt] = __builtin_amdgcn_mfma_f32_16x16x32_bf16(ah[mt], bl[ct], acc[ct][mt], 0, 0, 0);
                    acc[ct][mt] = __builtin_amdgcn_mfma_f32_16x16x32_bf16(al[mt], bh[ct], acc[ct][mt], 0, 0, 0);
                }
            if (ks < 13) {
                int nb = cur ^ 1;
#pragma unroll
                for (int it = 0; it < 2; it++) {
                    int idx = tid + it * 256;
                    int c = idx >> 2, oct = idx & 3;
                    *(uint4*)&BB[nb][0][c * 40 + oct * 8] = bregH[it];
                    *(uint4*)&BB[nb][1][c * 40 + oct * 8] = bregL[it];
                }
            }
            __syncthreads();
        }

        // ---- G exchange: U[128 c][33] <- acc; D: col=lane&15, row=4*(l>>4)+r ----
#pragma unroll
        for (int ct = 0; ct < 2; ct++)
#pragma unroll
            for (int mt = 0; mt < 2; mt++)
#pragma unroll
                for (int r = 0; r < 4; r++)
                    U[(w * 32 + ct * 16 + lr) * 33 + (mt * 16 + qa * 4 + r)] = acc[ct][mt][r];
        __syncthreads();

        // ---- LSTM pointwise ----
        {
            int b = tid & 31, hq = tid >> 5;   // hq 0..7
            unsigned short hh[4], hl[4];
#pragma unroll
            for (int q = 0; q < 4; q++) {
                int hlc = hq * 4 + q;          // 0..31
                int gb = hj * 32 + hlc;
                float iv = U[(0 * 32 + hlc) * 33 + b] + b_ih[gb]        + b_hh[gb];
                float fv = U[(1 * 32 + hlc) * 33 + b] + b_ih[256 + gb]  + b_hh[256 + gb];
                float gv = U[(2 * 32 + hlc) * 33 + b] + b_ih[512 + gb]  + b_hh[512 + gb];
                float ov = U[(3 * 32 + hlc) * 33 + b] + b_ih[768 + gb]  + b_hh[768 + gb];
                size_t cidx = (size_t)gb * 1024 + bg0 + b;
                float c_old = cx[cidx];
                float c_new = fmaf(sigmoidf_(fv), c_old, sigmoidf_(iv) * tanhf(gv));
                cx[cidx] = c_new;
                float hv = sigmoidf_(ov) * tanhf(c_new);
                hx_out[cidx] = hv;
                cvt_hl(hv, hh[q], hl[q]);
            }
            size_t ho = (size_t)(bg0 + b) * 256 + hj * 32 + hq * 4;
            *(ushort4*)&hxh_out[ho] = make_ushort4(hh[0], hh[1], hh[2], hh[3]);
            *(ushort4*)&hxl_out[ho] = make_ushort4(hl[0], hl[1], hl[2], hl[3]);
        }
    }
}

extern "C" void kernel_launch(void* const* d_in, const int* in_sizes, int n_in,
                              void* d_out, int out_size, void* d_ws, size_t ws_size,
                              hipStream_t stream) {
    const float* coords = (const float*)d_in[0];
    const float* pitch  = (const float*)d_in[1];
    const float* W_e1   = (const float*)d_in[2];
    const float* b_e1   = (const float*)d_in[3];
    const float* W_e2   = (const float*)d_in[4];
    const float* b_e2   = (const float*)d_in[5];
    const float* W_ih   = (const float*)d_in[6];
    const float* b_ih   = (const float*)d_in[7];
    const float* W_hh   = (const float*)d_in[8];
    const float* b_hh   = (const float*)d_in[9];
    const float* W_out  = (const float*)d_in[10];
    const float* b_out  = (const float*)d_in[11];
    float* out = (float*)d_out;
    float* ws  = (float*)d_ws;

    // ws layout (float offsets); total 19,814,912 floats ~= 79.3 MB
    float* hxA   = ws;                                            // 262144
    float* cxb   = ws + 262144;                                   // 262144
    unsigned short* hxhA = (unsigned short*)(ws + 524288);        // 131072 f
    unsigned short* hxlA = (unsigned short*)(ws + 655360);        // 131072 f
    float* hxB   = ws + 786432;                                   // 262144
    unsigned short* hxhB = (unsigned short*)(ws + 1048576);       // 131072 f
    unsigned short* hxlB = (unsigned short*)(ws + 1179648);       // 131072 f
    float* WoT   = ws + 1310720;                                  // 23040
    unsigned short* Wt_h = (unsigned short*)(ws + 1333760);       // 229376 f
    unsigned short* Wt_l = (unsigned short*)(ws + 1563136);       // 229376 f
    unsigned short* xin_h = (unsigned short*)(ws + 1792512);      // 18022400 f

    // zero hxA + cx + hxhA + hxlA (poisoned 0xAA by harness)
    hipMemsetAsync(ws, 0, (size_t)786432 * sizeof(float), stream);

    transpose_wout<<<90, 256, 0, stream>>>(W_out, WoT);
    prep_wt<<<1024, 256, 0, stream>>>(W_ih, W_hh, Wt_h, Wt_l);
    enc_kernel<<<SEQ * 16, 256, 0, stream>>>(coords, W_e1, b_e1, W_e2, b_e2, xin_h);

    for (int t = 0; t <= SEQ; t++) {
        bool even = !(t & 1);
        step_kernel<<<256, 256, 0, stream>>>(
            t, xin_h,
            even ? hxhA : hxhB, even ? hxlA : hxlB,
            even ? hxhB : hxhA, even ? hxlB : hxlA,
            even ? hxA : hxB, even ? hxB : hxA, cxb,
            Wt_h, Wt_l, b_ih, b_hh, WoT, b_out, pitch, out);
    }
}